// Round 2
// baseline (447.623 us; speedup 1.0000x reference)
//
#include <hip/hip_runtime.h>
#include <hip/hip_bf16.h>

// Problem constants (from reference setup_inputs):
//   rgb_feature:  (N=64, C=256, H=64, W=64) float32
//   skeleton_seq: (N=64, 3, T=64, V=25, M=2) float32
#define NN 64
#define CC 256
#define HH 64
#define WW 64
#define TT 64
#define VV 25
#define MM 2

// ---------------------------------------------------------------------------
// Kernel 1: per-sample gaussian center.
// thread n: argmax_v( mean_m ||mid[:,v,m] - first[:,v,m]||_2 ), then
// (x,y) = trunc(mid[0:2, v*, m=0] * {W,H}) -> xy[n], xy[NN+n]
// ---------------------------------------------------------------------------
__global__ void skel_center_kernel(const float* __restrict__ skel,
                                   float* __restrict__ xy) {
    int n = threadIdx.x;
    if (n >= NN) return;
    // strides for (N,3,T,V,M): sN = 3*T*V*M, sC = T*V*M, sT = V*M, sV = M, sM = 1
    const int sC = TT * VV * MM;   // 3200
    const int sT = VV * MM;        // 50
    const float* base = skel + n * 3 * sC;
    const float* mid = base + (TT / 2) * sT;

    int best_v = 0;
    float best_d = -1.0f;
#pragma unroll 5
    for (int v = 0; v < VV; ++v) {
        float sum = 0.0f;
#pragma unroll
        for (int m = 0; m < MM; ++m) {
            float s2 = 0.0f;
#pragma unroll
            for (int c = 0; c < 3; ++c) {
                float f0 = base[c * sC + v * MM + m];
                float fm = mid[c * sC + v * MM + m];
                float d = fm - f0;
                s2 += d * d;
            }
            sum += sqrtf(s2);
        }
        float dist = sum * 0.5f;  // mean over M=2
        if (dist > best_d) { best_d = dist; best_v = v; }  // strict > keeps first (JAX argmax tie rule)
    }
    float jx = mid[0 * sC + best_v * MM + 0];
    float jy = mid[1 * sC + best_v * MM + 0];
    xy[n]      = truncf(jx * (float)WW);
    xy[NN + n] = truncf(jy * (float)HH);
}

// ---------------------------------------------------------------------------
// Kernel 2: out[n,c,h,w] = rgb[n,c,h,w] * sigmoid(exp(-((w-x)^2+(h-y)^2)/(2*s^2)))
// float4 along W; grid-stride. All index math is shifts (dims are powers of 2).
// ---------------------------------------------------------------------------
__global__ void apply_mask_kernel(const float* __restrict__ rgb,
                                  const float* __restrict__ xy,
                                  float* __restrict__ out) {
    const float inv_2s2 = 1.0f / (2.0f * 9.6f * 9.6f);  // sigma = min(H,W)*0.15 = 9.6
    const int total4 = NN * CC * HH * WW / 4;           // 16,777,216
    int stride = gridDim.x * blockDim.x;
    for (int i = blockIdx.x * blockDim.x + threadIdx.x; i < total4; i += stride) {
        int n    = i >> 18;            // C*H*W/4 = 2^18 float4 per n
        int rem  = i & ((1 << 18) - 1);
        int hw4  = rem & 1023;         // H*W/4 = 1024 float4 per (n,c)
        int h    = hw4 >> 4;           // W/4 = 16 float4 per row
        int w0   = (hw4 & 15) << 2;

        float xp = xy[n];
        float yp = xy[NN + n];
        float dy = (float)h - yp;
        float dy2 = dy * dy;

        float4 r = reinterpret_cast<const float4*>(rgb)[i];
        float4 o;
#pragma unroll
        for (int j = 0; j < 4; ++j) {
            float dx = (float)(w0 + j) - xp;
            float g = __expf(-(dx * dx + dy2) * inv_2s2);
            float m = 1.0f / (1.0f + __expf(-g));  // sigmoid(g)
            (&o.x)[j] = (&r.x)[j] * m;
        }
        reinterpret_cast<float4*>(out)[i] = o;
    }
}

extern "C" void kernel_launch(void* const* d_in, const int* in_sizes, int n_in,
                              void* d_out, int out_size, void* d_ws, size_t ws_size,
                              hipStream_t stream) {
    const float* rgb  = (const float*)d_in[0];
    const float* skel = (const float*)d_in[1];
    float* out = (float*)d_out;
    float* xy  = (float*)d_ws;  // 2*NN floats of scratch

    skel_center_kernel<<<1, 64, 0, stream>>>(skel, xy);

    int block = 256;
    int grid = 4096;  // grid-stride: ~16 float4 iterations per thread
    apply_mask_kernel<<<grid, block, 0, stream>>>(rgb, xy, out);
}

// Round 3
// 430.710 us; speedup vs baseline: 1.0393x; 1.0393x over previous
//
#include <hip/hip_runtime.h>
#include <hip/hip_bf16.h>

// Problem constants:
//   rgb_feature:  (N=64, C=256, H=64, W=64) float32
//   skeleton_seq: (N=64, 3, T=64, V=25, M=2) float32
#define NN 64
#define CC 256
#define HH 64
#define WW 64
#define TT 64
#define VV 25
#define MM 2

typedef float f4 __attribute__((ext_vector_type(4)));

// ---------------------------------------------------------------------------
// Kernel 1: one block per sample n.
//   - lanes 0..24 of wave 0 compute dist[v] = mean_m ||mid - first||_2
//   - shfl_xor butterfly argmax (first-index tie rule: on equal d take min v)
//   - all 256 threads then fill mask[n][h][w] = sigmoid(exp(-r2/(2s^2)))
//     (N*H*W = 1 MB total, L2-resident, reused 256x across C by kernel 2)
// ---------------------------------------------------------------------------
__global__ __launch_bounds__(256) void build_mask_kernel(
    const float* __restrict__ skel, float* __restrict__ mask) {
    const int n  = blockIdx.x;
    const int sC = TT * VV * MM;   // 3200
    const int sT = VV * MM;        // 50
    const float* base = skel + n * 3 * sC;
    const float* mid  = base + (TT / 2) * sT;

    __shared__ float s_xy[2];
    const int tid = threadIdx.x;

    if (tid < 64) {
        float d = -1.0f;
        int   v = tid;
        if (tid < VV) {
            float sum = 0.0f;
#pragma unroll
            for (int m = 0; m < MM; ++m) {
                float s2 = 0.0f;
#pragma unroll
                for (int c = 0; c < 3; ++c) {
                    float f0 = base[c * sC + tid * MM + m];
                    float fm = mid [c * sC + tid * MM + m];
                    float df = fm - f0;
                    s2 += df * df;
                }
                sum += sqrtf(s2);
            }
            d = sum * 0.5f;  // mean over M=2
        }
        // butterfly argmax over the 32-lane group containing lanes 0..24
#pragma unroll
        for (int off = 16; off >= 1; off >>= 1) {
            float od = __shfl_xor(d, off, 32);
            int   ov = __shfl_xor(v, off, 32);
            if (od > d || (od == d && ov < v)) { d = od; v = ov; }
        }
        if (tid == 0) {
            float jx = mid[0 * sC + v * MM + 0];
            float jy = mid[1 * sC + v * MM + 0];
            s_xy[0] = truncf(jx * (float)WW);
            s_xy[1] = truncf(jy * (float)HH);
        }
    }
    __syncthreads();

    const float xp = s_xy[0];
    const float yp = s_xy[1];
    const float inv_2s2 = 1.0f / (2.0f * 9.6f * 9.6f);  // sigma = 9.6

    // 1024 float4 of mask for this n; 256 threads x 4 iterations
    for (int idx = tid; idx < HH * WW / 4; idx += 256) {
        int h  = idx >> 4;
        int w0 = (idx & 15) << 2;
        float dy  = (float)h - yp;
        float dy2 = dy * dy;
        f4 o;
#pragma unroll
        for (int j = 0; j < 4; ++j) {
            float dx = (float)(w0 + j) - xp;
            float g = __expf(-(dx * dx + dy2) * inv_2s2);
            o[j] = 1.0f / (1.0f + __expf(-g));  // sigmoid(g), same numerics as r1
        }
        reinterpret_cast<f4*>(mask)[(n << 10) | idx] = o;
    }
}

// ---------------------------------------------------------------------------
// Kernel 2: pure stream  out[i] = rgb[i] * mask[n,h,w]
// nontemporal on the 256 MB in/out streams; mask (1 MB) stays cached.
// ---------------------------------------------------------------------------
__global__ __launch_bounds__(256) void apply_mask_kernel(
    const float* __restrict__ rgb, const float* __restrict__ mask,
    float* __restrict__ out) {
    const int total4 = NN * CC * HH * WW / 4;  // 16,777,216
    const int stride = gridDim.x * blockDim.x;
    const f4* rgb4 = reinterpret_cast<const f4*>(rgb);
    const f4* m4   = reinterpret_cast<const f4*>(mask);
    f4* out4 = reinterpret_cast<f4*>(out);
    for (int i = blockIdx.x * blockDim.x + threadIdx.x; i < total4; i += stride) {
        int n   = i >> 18;     // C*H*W/4 float4 per n
        int hw4 = i & 1023;    // H*W/4 float4 per (n,c)
        f4 r = __builtin_nontemporal_load(&rgb4[i]);
        f4 m = m4[(n << 10) | hw4];
        f4 o = r * m;
        __builtin_nontemporal_store(o, &out4[i]);
    }
}

extern "C" void kernel_launch(void* const* d_in, const int* in_sizes, int n_in,
                              void* d_out, int out_size, void* d_ws, size_t ws_size,
                              hipStream_t stream) {
    const float* rgb  = (const float*)d_in[0];
    const float* skel = (const float*)d_in[1];
    float* out  = (float*)d_out;
    float* mask = (float*)d_ws;  // N*H*W floats = 1 MB scratch

    build_mask_kernel<<<NN, 256, 0, stream>>>(skel, mask);
    apply_mask_kernel<<<4096, 256, 0, stream>>>(rgb, mask, out);
}

// Round 4
// 423.048 us; speedup vs baseline: 1.0581x; 1.0181x over previous
//
#include <hip/hip_runtime.h>
#include <hip/hip_bf16.h>

// Problem constants:
//   rgb_feature:  (N=64, C=256, H=64, W=64) float32
//   skeleton_seq: (N=64, 3, T=64, V=25, M=2) float32
#define NN 64
#define CC 256
#define HH 64
#define WW 64
#define TT 64
#define VV 25
#define MM 2

typedef float f4 __attribute__((ext_vector_type(4)));

// ---------------------------------------------------------------------------
// Kernel 1: one block per sample n.
//   - lanes 0..24 of wave 0 compute dist[v] = mean_m ||mid - first||_2
//   - shfl_xor butterfly argmax (first-index tie rule: on equal d take min v)
//   - all 256 threads then fill mask[n][h][w] = sigmoid(exp(-r2/(2s^2)))
//     (N*H*W = 1 MB total, L2/L3-resident, reused by kernel 2)
// ---------------------------------------------------------------------------
__global__ __launch_bounds__(256) void build_mask_kernel(
    const float* __restrict__ skel, float* __restrict__ mask) {
    const int n  = blockIdx.x;
    const int sC = TT * VV * MM;   // 3200
    const int sT = VV * MM;        // 50
    const float* base = skel + n * 3 * sC;
    const float* mid  = base + (TT / 2) * sT;

    __shared__ float s_xy[2];
    const int tid = threadIdx.x;

    if (tid < 64) {
        float d = -1.0f;
        int   v = tid;
        if (tid < VV) {
            float sum = 0.0f;
#pragma unroll
            for (int m = 0; m < MM; ++m) {
                float s2 = 0.0f;
#pragma unroll
                for (int c = 0; c < 3; ++c) {
                    float f0 = base[c * sC + tid * MM + m];
                    float fm = mid [c * sC + tid * MM + m];
                    float df = fm - f0;
                    s2 += df * df;
                }
                sum += sqrtf(s2);
            }
            d = sum * 0.5f;  // mean over M=2
        }
        // butterfly argmax over the 32-lane group containing lanes 0..24
#pragma unroll
        for (int off = 16; off >= 1; off >>= 1) {
            float od = __shfl_xor(d, off, 32);
            int   ov = __shfl_xor(v, off, 32);
            if (od > d || (od == d && ov < v)) { d = od; v = ov; }
        }
        if (tid == 0) {
            float jx = mid[0 * sC + v * MM + 0];
            float jy = mid[1 * sC + v * MM + 0];
            s_xy[0] = truncf(jx * (float)WW);
            s_xy[1] = truncf(jy * (float)HH);
        }
    }
    __syncthreads();

    const float xp = s_xy[0];
    const float yp = s_xy[1];
    const float inv_2s2 = 1.0f / (2.0f * 9.6f * 9.6f);  // sigma = 9.6

    for (int idx = tid; idx < HH * WW / 4; idx += 256) {
        int h  = idx >> 4;
        int w0 = (idx & 15) << 2;
        float dy  = (float)h - yp;
        float dy2 = dy * dy;
        f4 o;
#pragma unroll
        for (int j = 0; j < 4; ++j) {
            float dx = (float)(w0 + j) - xp;
            float g = __expf(-(dx * dx + dy2) * inv_2s2);
            o[j] = 1.0f / (1.0f + __expf(-g));  // sigmoid(g)
        }
        reinterpret_cast<f4*>(mask)[(n << 10) | idx] = o;
    }
}

// ---------------------------------------------------------------------------
// Kernel 2: pure stream  out = rgb * mask, mask register-cached per thread.
// Block b: n = b>>4, q = (b>>2)&3 (64-channel slice), hb = b&3 (hw4 chunk).
// Thread owns one (n, hw4) pair, loads mask ONCE, streams 64 channels
// (plane stride 1024 float4 = 4 KB; each access is 1 KB/wave contiguous).
// ---------------------------------------------------------------------------
__global__ __launch_bounds__(256) void apply_mask_kernel(
    const float* __restrict__ rgb, const float* __restrict__ mask,
    float* __restrict__ out) {
    const int b   = blockIdx.x;
    const int n   = b >> 4;
    const int q   = (b >> 2) & 3;   // channel quarter: c in [q*64, q*64+64)
    const int hb  = b & 3;          // hw4 chunk
    const int hw4 = (hb << 8) | threadIdx.x;  // 0..1023

    const f4 m = reinterpret_cast<const f4*>(mask)[(n << 10) | hw4];

    // float4 index of (n, c=q*64, hw4)
    int i = (n << 18) | (q << 16) | hw4;
    const f4* rgb4 = reinterpret_cast<const f4*>(rgb);
    f4* out4 = reinterpret_cast<f4*>(out);

#pragma unroll 8
    for (int c = 0; c < 64; ++c) {
        f4 r = __builtin_nontemporal_load(&rgb4[i]);
        f4 o = r * m;
        __builtin_nontemporal_store(o, &out4[i]);
        i += 1024;  // next channel plane
    }
}

extern "C" void kernel_launch(void* const* d_in, const int* in_sizes, int n_in,
                              void* d_out, int out_size, void* d_ws, size_t ws_size,
                              hipStream_t stream) {
    const float* rgb  = (const float*)d_in[0];
    const float* skel = (const float*)d_in[1];
    float* out  = (float*)d_out;
    float* mask = (float*)d_ws;  // N*H*W floats = 1 MB scratch

    build_mask_kernel<<<NN, 256, 0, stream>>>(skel, mask);
    apply_mask_kernel<<<NN * 16, 256, 0, stream>>>(rgb, mask, out);
}